// Round 2
// baseline (372.955 us; speedup 1.0000x reference)
//
#include <hip/hip_runtime.h>
#include <math.h>

// Fused two-head classifier via bf16 MFMA GEMM:
//   C[65536 x 48] = embs[65536 x 1024] (bf16-cast) x B[1024 x 48]
//   B cols 0..4 = W_status, 5..34 = W_flight, 35..47 = zero pad.
//   Epilogue: dual softmax + gating via 16-lane shuffle butterflies
//   (C/D layout: col = lane&15, row = (lane>>4)*4 + reg).
//
// Per wave: 16 rows, full K=1024 (32 k-steps x 3 mfma_f32_16x16x32_bf16).
// A fragments loaded straight from global (lane = row n=lane&15,
// k-chunk (lane>>4)*8) with next-PAIR prefetch; each row's 128B line region
// is fully consumed per k-step -> embs read exactly once (268 MB).
// B staged per K-half into 48 KB LDS in fragment order -> stride-1
// ds_read_b128 with offset immediates, no scalar loads in the hot loop.
//
// R1: k-phase rotation (verified +19 us end-to-end) breaks the stride-4096
// HBM channel-phase lock (all blocks/waves previously walked k in lock-step,
// concentrating traffic on a rotating channel subset).
//
// R2 (this round): pair the k-steps to cut per-step issue overhead. The
// rotation made every A-address a runtime scalar (no offset-immediate
// folding), leaving the kernel marginally VALU-issue-bound (~49-cyc budget
// per SIMD slot at HBM rate vs ~50+ cyc of MFMA+VALU issue). Rotating in
// units of 2 k-steps keeps the same instantaneous channel coverage
// (8 phases x 256 B == 16 x 128 B) while halving address builds: per pair,
// ONE 64-bit global address + 4 dwordx4 at offset:0/16/128/144, and ONE
// LDS base + 6 ds_read_b128 at offset:0..5120.

typedef __bf16 bf16x8 __attribute__((ext_vector_type(8)));
typedef float  f32x4  __attribute__((ext_vector_type(4)));

#define ROWS_PER_BLOCK 256   // 16 waves * 16 rows
#define KSTEPS    32         // 1024 / 32
#define HALF_KS   16
#define HALF_PAIRS 8

__global__ __launch_bounds__(1024, 4)
void fused_heads_kernel(const float* __restrict__ embs,
                        const float* __restrict__ W_status,
                        const float* __restrict__ b_status,
                        const float* __restrict__ W_flight,
                        const float* __restrict__ b_flight,
                        float* __restrict__ out) {
    // B half-tile: [16 ks][3 frag][64 lanes] x 16B = 48 KB
    __shared__ bf16x8 Bsh[HALF_KS * 3 * 64];

    const int tid  = threadIdx.x;
    const int lane = tid & 63;
    const int wv   = tid >> 6;          // 0..15
    const int n    = lane & 15;         // MFMA row (A) / col (C)
    const int q    = lane >> 4;         // quad group 0..3

    const int rowbase = blockIdx.x * ROWS_PER_BLOCK + wv * 16;
    const float* aptr = embs + (size_t)(rowbase + n) * 1024 + q * 8;

    // --- k-phase decorrelation (pair granularity) ---
    const int proffs = (wv + (int)blockIdx.x * 3) & 7;  // per-wave pair rotation
    const int h0     = (int)blockIdx.x & 1;             // per-block half order

    f32x4 acc0 = {0.f, 0.f, 0.f, 0.f};
    f32x4 acc1 = {0.f, 0.f, 0.f, 0.f};
    f32x4 acc2 = {0.f, 0.f, 0.f, 0.f};

    // prefetch A for the first (rotated) pair: global pair gp covers
    // k-steps 2*gp and 2*gp+1, i.e. floats [gp*64, gp*64+64) per row.
    {
        const int gp0 = h0 * HALF_PAIRS + proffs;
        const float* p0 = aptr + gp0 * 64;
        // loads fold to one address + offset:0/16/128/144
        (void)p0;
    }
    const float* pf0 = aptr + (h0 * HALF_PAIRS + proffs) * 64;
    float4 ca0 = *(const float4*)(pf0);
    float4 ca1 = *(const float4*)(pf0 + 4);
    float4 ca2 = *(const float4*)(pf0 + 32);
    float4 ca3 = *(const float4*)(pf0 + 36);

    for (int ph = 0; ph < 2; ++ph) {
        const int h = h0 ^ ph;          // actual K-half being processed
        __syncthreads();   // previous half's Bsh reads finished

        // ---- stage B half h (3072 frags, 3 per thread), coalesced LDS writes ----
#pragma unroll
        for (int i = 0; i < 3; ++i) {
            const int d   = tid + i * 1024;
            const int L   = d & 63;
            const int ksf = d >> 6;                    // 0..47 = ksl*3 + f
            const int ksl = ksf / 3;
            const int f   = ksf - ksl * 3;
            const int bn  = f * 16 + (L & 15);         // B column 0..47
            const int bk  = (h * HALF_KS + ksl) * 32 + (L >> 4) * 8;
            bf16x8 w;
#pragma unroll
            for (int j = 0; j < 8; ++j) w[j] = (__bf16)0.0f;
            if (bn < 35) {
                const float* src = (bn < 5) ? (W_status + bn * 1024 + bk)
                                            : (W_flight + (bn - 5) * 1024 + bk);
                const float4 w0 = *(const float4*)(src);
                const float4 w1 = *(const float4*)(src + 4);
                w[0] = (__bf16)w0.x; w[1] = (__bf16)w0.y;
                w[2] = (__bf16)w0.z; w[3] = (__bf16)w0.w;
                w[4] = (__bf16)w1.x; w[5] = (__bf16)w1.y;
                w[6] = (__bf16)w1.z; w[7] = (__bf16)w1.w;
            }
            Bsh[d] = w;
        }
        __syncthreads();   // Bsh half visible

        // ---- 8 rotated PAIRS (16 k-steps): prefetch next pair, 2x(cvt + 3 MFMA) ----
#pragma unroll 4
        for (int pl = 0; pl < HALF_PAIRS; ++pl) {
            const int psl = (pl + proffs) & 7;         // rotated pair within half
            int ngp;                                   // next global pair (wave-uniform)
            if (pl < HALF_PAIRS - 1)  ngp = h * HALF_PAIRS + ((pl + 1 + proffs) & 7);
            else if (ph == 0)         ngp = (h0 ^ 1) * HALF_PAIRS + proffs;
            else                      ngp = h * HALF_PAIRS + psl;   // clamp, no OOB
            const float* np = aptr + ngp * 64;
            const float4 na0 = *(const float4*)(np);
            const float4 na1 = *(const float4*)(np + 4);
            const float4 na2 = *(const float4*)(np + 32);
            const float4 na3 = *(const float4*)(np + 36);

            // B fragments: one base, 6 reads at offset 0,1024,...,5120
            const bf16x8* bp = &Bsh[(psl * 6) * 64 + lane];

            bf16x8 af0;
            af0[0] = (__bf16)ca0.x; af0[1] = (__bf16)ca0.y;
            af0[2] = (__bf16)ca0.z; af0[3] = (__bf16)ca0.w;
            af0[4] = (__bf16)ca1.x; af0[5] = (__bf16)ca1.y;
            af0[6] = (__bf16)ca1.z; af0[7] = (__bf16)ca1.w;

            acc0 = __builtin_amdgcn_mfma_f32_16x16x32_bf16(af0, bp[0],   acc0, 0, 0, 0);
            acc1 = __builtin_amdgcn_mfma_f32_16x16x32_bf16(af0, bp[64],  acc1, 0, 0, 0);
            acc2 = __builtin_amdgcn_mfma_f32_16x16x32_bf16(af0, bp[128], acc2, 0, 0, 0);

            bf16x8 af1;
            af1[0] = (__bf16)ca2.x; af1[1] = (__bf16)ca2.y;
            af1[2] = (__bf16)ca2.z; af1[3] = (__bf16)ca2.w;
            af1[4] = (__bf16)ca3.x; af1[5] = (__bf16)ca3.y;
            af1[6] = (__bf16)ca3.z; af1[7] = (__bf16)ca3.w;

            acc0 = __builtin_amdgcn_mfma_f32_16x16x32_bf16(af1, bp[192], acc0, 0, 0, 0);
            acc1 = __builtin_amdgcn_mfma_f32_16x16x32_bf16(af1, bp[256], acc1, 0, 0, 0);
            acc2 = __builtin_amdgcn_mfma_f32_16x16x32_bf16(af1, bp[320], acc2, 0, 0, 0);

            ca0 = na0; ca1 = na1; ca2 = na2; ca3 = na3;
        }
    }

    // ---- epilogue: per-row dual softmax across the 16-lane group ----
    // lane holds cols n, 16+n, 32+n for rows q*4+i (i = 0..3).
    const float bias0 = (n < 5) ? b_status[n] : b_flight[n - 5];
    const float bias1 = b_flight[n + 11];
    const float bias2 = (n < 3) ? b_flight[n + 27] : 0.0f;
    const int   gb    = lane & 48;   // group base lane

#pragma unroll
    for (int i = 0; i < 4; ++i) {
        const float v0 = acc0[i] + bias0;                       // col n
        const float v1 = acc1[i] + bias1;                       // col 16+n
        const float v2 = (n < 3) ? (acc2[i] + bias2) : -INFINITY; // col 32+n

        float ms = (n < 5) ? v0 : -INFINITY;                    // status max
        float mf = fmaxf((n >= 5) ? v0 : -INFINITY, fmaxf(v1, v2)); // flight max
#pragma unroll
        for (int m = 1; m < 16; m <<= 1) {
            ms = fmaxf(ms, __shfl_xor(ms, m));
            mf = fmaxf(mf, __shfl_xor(mf, m));
        }

        const float es  = (n < 5)  ? __expf(v0 - ms) : 0.0f;
        const float ef0 = (n >= 5) ? __expf(v0 - mf) : 0.0f;
        const float ef1 = __expf(v1 - mf);
        const float ef2 = (n < 3)  ? __expf(v2 - mf) : 0.0f;

        float ss = es;
        float sf = ef0 + ef1 + ef2;
#pragma unroll
        for (int m = 1; m < 16; m <<= 1) {
            ss += __shfl_xor(ss, m);
            sf += __shfl_xor(sf, m);
        }
        const float invs = 1.0f / ss;
        const float invf = 1.0f / sf;

        const float book   = __shfl(es, gb + 4) * invs * invf;  // s4 * invs * invf
        const float change = __shfl(es, gb + 3) * invs * invf;  // s3 * invs * invf

        float* orow = out + (size_t)(rowbase + q * 4 + i) * 63;
        if (n == 0) orow[0] = es * invs;            // no_flight  (status 0)
        if (n == 2) orow[1] = es * invs;            // cancel     (status 2)
        if (n == 1) orow[2] = es * invs;            // no_reservation (status 1)
        if (n >= 5) {                               // flight j = n-5  (cols 5..15)
            orow[3 + (n - 5)]  = book   * ef0;
            orow[33 + (n - 5)] = change * ef0;
        }
        orow[3 + (n + 11)]  = book   * ef1;         // flight j = n+11 (cols 16..31)
        orow[33 + (n + 11)] = change * ef1;
        if (n < 3) {                                // flight j = n+27 (cols 32..34)
            orow[3 + (n + 27)]  = book   * ef2;
            orow[33 + (n + 27)] = change * ef2;
        }
    }
}

extern "C" void kernel_launch(void* const* d_in, const int* in_sizes, int n_in,
                              void* d_out, int out_size, void* d_ws, size_t ws_size,
                              hipStream_t stream) {
    const float* embs     = (const float*)d_in[0];
    const float* W_status = (const float*)d_in[1];
    const float* b_status = (const float*)d_in[2];
    const float* W_flight = (const float*)d_in[3];
    const float* b_flight = (const float*)d_in[4];
    float* out = (float*)d_out;

    const int rows = in_sizes[0] / 1024;              // 65536
    const int grid = rows / ROWS_PER_BLOCK;           // 256

    fused_heads_kernel<<<grid, 1024, 0, stream>>>(
        embs, W_status, b_status, W_flight, b_flight, out);
}